// Round 5
// baseline (62.271 us; speedup 1.0000x reference)
//
#include <hip/hip_runtime.h>

#define CS 384
#define CH 32
#define CZ 128
#define LL 512
#define C4 (CZ * CH)   // 4096 combined (z,a) columns
#define EPSV 1e-5f

typedef __attribute__((ext_vector_type(8))) short bf16x8;
typedef __attribute__((ext_vector_type(4))) float f32x4;

static __device__ __forceinline__ unsigned short f2bf(float x) {
  union { float f; unsigned int u; } c; c.f = x;
  unsigned int r = c.u + 0x7FFFu + ((c.u >> 16) & 1u);  // RNE
  return (unsigned short)(r >> 16);
}
static __device__ __forceinline__ unsigned int pk2(float lo, float hi) {
  return (unsigned int)f2bf(lo) | ((unsigned int)f2bf(hi) << 16);
}

// ---------------- Kernel 1: LayerNorm + two projections -> bf16 A,B ----------
__global__ __launch_bounds__(256) void ln_proj_kernel(
    const float* __restrict__ s, const float* __restrict__ gamma,
    const float* __restrict__ beta,
    const float* __restrict__ w1, const float* __restrict__ b1,
    const float* __restrict__ w2, const float* __restrict__ b2,
    unsigned short* __restrict__ Abf, unsigned short* __restrict__ Bbf) {
  int l = blockIdx.x;
  int tid = threadIdx.x;
  __shared__ float sn[CS];
  __shared__ float wred[8];
  __shared__ float red[256];
  const float* srow = s + l * CS;

  float lsum = 0.f, lsq = 0.f;
  for (int c = tid; c < CS; c += 256) {
    float x = srow[c]; sn[c] = x; lsum += x; lsq += x * x;
  }
  #pragma unroll
  for (int off = 32; off > 0; off >>= 1) {
    lsum += __shfl_down(lsum, off);
    lsq  += __shfl_down(lsq, off);
  }
  int wv = tid >> 6;
  if ((tid & 63) == 0) { wred[wv] = lsum; wred[4 + wv] = lsq; }
  __syncthreads();
  float s1 = wred[0] + wred[1] + wred[2] + wred[3];
  float s2 = wred[4] + wred[5] + wred[6] + wred[7];
  float mu = s1 * (1.0f / CS);
  float var = s2 * (1.0f / CS) - mu * mu;
  float rstd = rsqrtf(var + EPSV);

  for (int c = tid; c < CS; c += 256)
    sn[c] = (sn[c] - mu) * rstd * gamma[c] + beta[c];
  __syncthreads();

  // 64 outputs (h<32: A via w1, else B via w2), 4 c-chunks of 96 per output.
  int o = tid & 63, q = tid >> 6;
  int h = o & 31;
  const float* w = (o < CH) ? w1 : w2;
  float acc = 0.f;
  int c0 = q * 96;
  #pragma unroll 8
  for (int c = c0; c < c0 + 96; ++c) acc += sn[c] * w[c * CH + h];
  red[tid] = acc; __syncthreads();
  if (tid < 64) {
    float r = red[tid] + red[tid + 64] + red[tid + 128] + red[tid + 192];
    if (o < CH) Abf[l * CH + h] = f2bf(r + b1[h]);
    else        Bbf[l * CH + h] = f2bf(r + b2[h]);
  }
}

// ---------------- Kernel 2: W[a][b][z] fp32 -> Wt[z*32+a][b] bf16 -------------
__global__ __launch_bounds__(256) void wtrans_kernel(
    const float* __restrict__ w_out, unsigned short* __restrict__ Wt) {
  int a = blockIdx.x;  // 0..31
  int tid = threadIdx.x;
  __shared__ float Wl[CH * CZ];  // [b][z]
  const float4* Wg = (const float4*)(w_out + (size_t)a * CH * CZ);
  float4* Wl4 = (float4*)Wl;
  #pragma unroll
  for (int v = 0; v < 4; ++v) Wl4[tid + v * 256] = Wg[tid + v * 256];
  __syncthreads();
  int z = tid >> 1, bh = tid & 1;  // z 0..127, b-half 0..1
  unsigned int dw[8];
  #pragma unroll
  for (int k = 0; k < 8; ++k) {
    unsigned short lo = f2bf(Wl[(bh * 16 + 2 * k) * CZ + z]);
    unsigned short hi = f2bf(Wl[(bh * 16 + 2 * k + 1) * CZ + z]);
    dw[k] = (unsigned int)lo | ((unsigned int)hi << 16);
  }
  unsigned int* dst =
      (unsigned int*)((char*)Wt + ((size_t)z * CH + a) * 64 + bh * 32);
  *(uint4*)dst = make_uint4(dw[0], dw[1], dw[2], dw[3]);
  *(uint4*)(dst + 4) = make_uint4(dw[4], dw[5], dw[6], dw[7]);
}

// ---------------- Kernel 3: Tt[j][c] = sum_b Bbf[j,b] * Wt[c,b] (bf16 out) ----
// One wave per block; swapped-operand MFMA so rows c land contiguous per lane.
__global__ __launch_bounds__(64) void tmat_kernel(
    const unsigned short* __restrict__ Bbf, const unsigned short* __restrict__ Wt,
    unsigned short* __restrict__ Tt) {
  int jt = blockIdx.x;   // 0..31 -> 16 j's
  int cq = blockIdx.y;   // 0..31 -> 8 c-tiles of 16
  int l = threadIdx.x;
  int q = l >> 4, r = l & 15;
  bf16x8 bfrag = *(const bf16x8*)(Bbf + (size_t)(jt * 16 + r) * CH + 8 * q);
  int j = jt * 16 + r;
  f32x4 zer = {0.f, 0.f, 0.f, 0.f};
  #pragma unroll
  for (int t = 0; t < 8; ++t) {
    int cbase = cq * 128 + t * 16;
    bf16x8 wfrag = *(const bf16x8*)(Wt + (size_t)(cbase + r) * CH + 8 * q);
    f32x4 acc = __builtin_amdgcn_mfma_f32_16x16x32_bf16(wfrag, bfrag, zer, 0, 0, 0);
    // D: col = r -> j, rows = cbase + 4q + reg (4 consecutive c).
    uint2 st;
    st.x = pk2(acc[0], acc[1]);
    st.y = pk2(acc[2], acc[3]);
    *(uint2*)(&Tt[(size_t)j * C4 + cbase + 4 * q]) = st;
  }
}

// ---------------- Kernel 4: out[i,j,:] = A[i,:] . T[j,:,:] + b_out ------------
// No LDS, no barriers. Grid (4 it, 512 j), 4 waves/block, wave owns 32 i.
// MFMA: D = Tt_j^T-frag (z x a) . A-frag (a x i), C = bias. One MFMA per tile.
__global__ __launch_bounds__(256) void outer_mfma(
    const unsigned short* __restrict__ Abf, const unsigned short* __restrict__ Tt,
    const float* __restrict__ b_out, float* __restrict__ out) {
  int it = blockIdx.x;  // 0..3
  int j  = blockIdx.y;  // 0..511
  int tid = threadIdx.x;
  int w = tid >> 6, l = tid & 63, q = l >> 4, r = l & 15;
  int ib = it * 128 + w * 32;

  bf16x8 af0 = *(const bf16x8*)(Abf + (size_t)(ib + r) * CH + 8 * q);
  bf16x8 af1 = *(const bf16x8*)(Abf + (size_t)(ib + 16 + r) * CH + 8 * q);
  const unsigned short* Tj = Tt + (size_t)j * C4;

  #pragma unroll
  for (int zt = 0; zt < 8; ++zt) {
    f32x4 bo = *(const f32x4*)(b_out + zt * 16 + 4 * q);
    bf16x8 tf = *(const bf16x8*)(Tj + (size_t)(zt * 16 + r) * CH + 8 * q);
    f32x4 a0 = __builtin_amdgcn_mfma_f32_16x16x32_bf16(tf, af0, bo, 0, 0, 0);
    f32x4 a1 = __builtin_amdgcn_mfma_f32_16x16x32_bf16(tf, af1, bo, 0, 0, 0);
    // D: col = r -> i, rows = zt*16 + 4q + reg -> 4 consecutive z.
    float* o0 = out + ((size_t)(ib + r) * LL + j) * CZ + zt * 16 + 4 * q;
    float* o1 = out + ((size_t)(ib + 16 + r) * LL + j) * CZ + zt * 16 + 4 * q;
    __builtin_nontemporal_store(a0, (f32x4*)o0);
    __builtin_nontemporal_store(a1, (f32x4*)o1);
  }
}

extern "C" void kernel_launch(void* const* d_in, const int* in_sizes, int n_in,
                              void* d_out, int out_size, void* d_ws, size_t ws_size,
                              hipStream_t stream) {
  const float* s     = (const float*)d_in[0];
  const float* gam   = (const float*)d_in[1];
  const float* bet   = (const float*)d_in[2];
  const float* w1    = (const float*)d_in[3];
  const float* b1    = (const float*)d_in[4];
  const float* w2    = (const float*)d_in[5];
  const float* b2    = (const float*)d_in[6];
  const float* w_out = (const float*)d_in[7];
  const float* b_out = (const float*)d_in[8];
  float* out = (float*)d_out;

  char* ws = (char*)d_ws;
  unsigned short* Abf = (unsigned short*)(ws);            // 32 KB
  unsigned short* Bbf = (unsigned short*)(ws + 32768);    // 32 KB
  unsigned short* Wt  = (unsigned short*)(ws + 65536);    // 256 KB
  unsigned short* Tt  = (unsigned short*)(ws + 327680);   // 4 MB

  ln_proj_kernel<<<LL, 256, 0, stream>>>(s, gam, bet, w1, b1, w2, b2, Abf, Bbf);
  wtrans_kernel<<<CH, 256, 0, stream>>>(w_out, Wt);
  tmat_kernel<<<dim3(32, 32), 64, 0, stream>>>(Bbf, Wt, Tt);
  outer_mfma<<<dim3(4, LL), 256, 0, stream>>>(Abf, Tt, b_out, out);
}

// Round 6
// 46.964 us; speedup vs baseline: 1.3259x; 1.3259x over previous
//
#include <hip/hip_runtime.h>

#define CS 384
#define CH 32
#define CZ 128
#define LL 512
#define C4 (CZ * CH)   // 4096 combined (z,a) columns
#define EPSV 1e-5f

typedef __attribute__((ext_vector_type(8))) short bf16x8;
typedef __attribute__((ext_vector_type(4))) float f32x4;

static __device__ __forceinline__ unsigned short f2bf(float x) {
  union { float f; unsigned int u; } c; c.f = x;
  unsigned int r = c.u + 0x7FFFu + ((c.u >> 16) & 1u);  // RNE
  return (unsigned short)(r >> 16);
}
static __device__ __forceinline__ unsigned int pk2(float lo, float hi) {
  return (unsigned int)f2bf(lo) | ((unsigned int)f2bf(hi) << 16);
}

// ---------------- Kernel 1: LayerNorm + two projections -> bf16 A,B ----------
__global__ __launch_bounds__(256) void ln_proj_kernel(
    const float* __restrict__ s, const float* __restrict__ gamma,
    const float* __restrict__ beta,
    const float* __restrict__ w1, const float* __restrict__ b1,
    const float* __restrict__ w2, const float* __restrict__ b2,
    unsigned short* __restrict__ Abf, unsigned short* __restrict__ Bbf) {
  int l = blockIdx.x;
  int tid = threadIdx.x;
  __shared__ float sn[CS];
  __shared__ float wred[8];
  __shared__ float red[256];
  const float* srow = s + l * CS;

  float lsum = 0.f, lsq = 0.f;
  for (int c = tid; c < CS; c += 256) {
    float x = srow[c]; sn[c] = x; lsum += x; lsq += x * x;
  }
  #pragma unroll
  for (int off = 32; off > 0; off >>= 1) {
    lsum += __shfl_down(lsum, off);
    lsq  += __shfl_down(lsq, off);
  }
  int wv = tid >> 6;
  if ((tid & 63) == 0) { wred[wv] = lsum; wred[4 + wv] = lsq; }
  __syncthreads();
  float s1 = wred[0] + wred[1] + wred[2] + wred[3];
  float s2 = wred[4] + wred[5] + wred[6] + wred[7];
  float mu = s1 * (1.0f / CS);
  float var = s2 * (1.0f / CS) - mu * mu;
  float rstd = rsqrtf(var + EPSV);

  for (int c = tid; c < CS; c += 256)
    sn[c] = (sn[c] - mu) * rstd * gamma[c] + beta[c];
  __syncthreads();

  // 64 outputs (h<32: A via w1, else B via w2), 4 c-chunks of 96 per output.
  int o = tid & 63, q = tid >> 6;
  int h = o & 31;
  const float* w = (o < CH) ? w1 : w2;
  float acc = 0.f;
  int c0 = q * 96;
  #pragma unroll 8
  for (int c = c0; c < c0 + 96; ++c) acc += sn[c] * w[c * CH + h];
  red[tid] = acc; __syncthreads();
  if (tid < 64) {
    float r = red[tid] + red[tid + 64] + red[tid + 128] + red[tid + 192];
    if (o < CH) Abf[l * CH + h] = f2bf(r + b1[h]);
    else        Bbf[l * CH + h] = f2bf(r + b2[h]);
  }
}

// ---------------- Kernel 2: W[a][b][z] fp32 -> Wt[z*32+a][b] bf16 -------------
__global__ __launch_bounds__(256) void wtrans_kernel(
    const float* __restrict__ w_out, unsigned short* __restrict__ Wt) {
  int a = blockIdx.x;  // 0..31
  int tid = threadIdx.x;
  __shared__ float Wl[CH * CZ];  // [b][z]
  const float4* Wg = (const float4*)(w_out + (size_t)a * CH * CZ);
  float4* Wl4 = (float4*)Wl;
  #pragma unroll
  for (int v = 0; v < 4; ++v) Wl4[tid + v * 256] = Wg[tid + v * 256];
  __syncthreads();
  int z = tid >> 1, bh = tid & 1;  // z 0..127, b-half 0..1
  unsigned int dw[8];
  #pragma unroll
  for (int k = 0; k < 8; ++k) {
    unsigned short lo = f2bf(Wl[(bh * 16 + 2 * k) * CZ + z]);
    unsigned short hi = f2bf(Wl[(bh * 16 + 2 * k + 1) * CZ + z]);
    dw[k] = (unsigned int)lo | ((unsigned int)hi << 16);
  }
  unsigned int* dst =
      (unsigned int*)((char*)Wt + ((size_t)z * CH + a) * 64 + bh * 32);
  *(uint4*)dst = make_uint4(dw[0], dw[1], dw[2], dw[3]);
  *(uint4*)(dst + 4) = make_uint4(dw[4], dw[5], dw[6], dw[7]);
}

// ---------------- Kernel 3: Tt[j][c] = sum_b Bbf[j,b] * Wt[c,b] (bf16 out) ----
__global__ __launch_bounds__(64) void tmat_kernel(
    const unsigned short* __restrict__ Bbf, const unsigned short* __restrict__ Wt,
    unsigned short* __restrict__ Tt) {
  int jt = blockIdx.x;   // 0..31 -> 16 j's
  int cq = blockIdx.y;   // 0..31 -> 8 c-tiles of 16
  int l = threadIdx.x;
  int q = l >> 4, r = l & 15;
  bf16x8 bfrag = *(const bf16x8*)(Bbf + (size_t)(jt * 16 + r) * CH + 8 * q);
  int j = jt * 16 + r;
  f32x4 zer = {0.f, 0.f, 0.f, 0.f};
  #pragma unroll
  for (int t = 0; t < 8; ++t) {
    int cbase = cq * 128 + t * 16;
    bf16x8 wfrag = *(const bf16x8*)(Wt + (size_t)(cbase + r) * CH + 8 * q);
    f32x4 acc = __builtin_amdgcn_mfma_f32_16x16x32_bf16(wfrag, bfrag, zer, 0, 0, 0);
    // D: col = r -> j, rows = cbase + 4q + reg (4 consecutive c).
    uint2 st;
    st.x = pk2(acc[0], acc[1]);
    st.y = pk2(acc[2], acc[3]);
    *(uint2*)(&Tt[(size_t)j * C4 + cbase + 4 * q]) = st;
  }
}

// ---------------- Kernel 4: out[i,j,:] = A[i,:] . T[j,:,:] + b_out ------------
// No LDS, no barriers. Grid (4 it, 512 j), 4 waves/block, wave owns 32 i.
// MFMA: D = Tt_j^T-frag (z x a) . A-frag (a x i), C = bias. One MFMA per tile.
// Plain f32x4 stores (L2 write-aggregated; nt-store regressed 13 us in R5).
__global__ __launch_bounds__(256) void outer_mfma(
    const unsigned short* __restrict__ Abf, const unsigned short* __restrict__ Tt,
    const float* __restrict__ b_out, float* __restrict__ out) {
  int it = blockIdx.x;  // 0..3
  int j  = blockIdx.y;  // 0..511
  int tid = threadIdx.x;
  int w = tid >> 6, l = tid & 63, q = l >> 4, r = l & 15;
  int ib = it * 128 + w * 32;

  bf16x8 af0 = *(const bf16x8*)(Abf + (size_t)(ib + r) * CH + 8 * q);
  bf16x8 af1 = *(const bf16x8*)(Abf + (size_t)(ib + 16 + r) * CH + 8 * q);
  const unsigned short* Tj = Tt + (size_t)j * C4;

  #pragma unroll
  for (int zt = 0; zt < 8; ++zt) {
    f32x4 bo = *(const f32x4*)(b_out + zt * 16 + 4 * q);
    bf16x8 tf = *(const bf16x8*)(Tj + (size_t)(zt * 16 + r) * CH + 8 * q);
    f32x4 a0 = __builtin_amdgcn_mfma_f32_16x16x32_bf16(tf, af0, bo, 0, 0, 0);
    f32x4 a1 = __builtin_amdgcn_mfma_f32_16x16x32_bf16(tf, af1, bo, 0, 0, 0);
    // D: col = r -> i, rows = zt*16 + 4q + reg -> 4 consecutive z.
    float* o0 = out + ((size_t)(ib + r) * LL + j) * CZ + zt * 16 + 4 * q;
    float* o1 = out + ((size_t)(ib + 16 + r) * LL + j) * CZ + zt * 16 + 4 * q;
    *(f32x4*)o0 = a0;
    *(f32x4*)o1 = a1;
  }
}

extern "C" void kernel_launch(void* const* d_in, const int* in_sizes, int n_in,
                              void* d_out, int out_size, void* d_ws, size_t ws_size,
                              hipStream_t stream) {
  const float* s     = (const float*)d_in[0];
  const float* gam   = (const float*)d_in[1];
  const float* bet   = (const float*)d_in[2];
  const float* w1    = (const float*)d_in[3];
  const float* b1    = (const float*)d_in[4];
  const float* w2    = (const float*)d_in[5];
  const float* b2    = (const float*)d_in[6];
  const float* w_out = (const float*)d_in[7];
  const float* b_out = (const float*)d_in[8];
  float* out = (float*)d_out;

  char* ws = (char*)d_ws;
  unsigned short* Abf = (unsigned short*)(ws);            // 32 KB
  unsigned short* Bbf = (unsigned short*)(ws + 32768);    // 32 KB
  unsigned short* Wt  = (unsigned short*)(ws + 65536);    // 256 KB
  unsigned short* Tt  = (unsigned short*)(ws + 327680);   // 4 MB

  ln_proj_kernel<<<LL, 256, 0, stream>>>(s, gam, bet, w1, b1, w2, b2, Abf, Bbf);
  wtrans_kernel<<<CH, 256, 0, stream>>>(w_out, Wt);
  tmat_kernel<<<dim3(32, 32), 64, 0, stream>>>(Bbf, Wt, Tt);
  outer_mfma<<<dim3(4, LL), 256, 0, stream>>>(Abf, Tt, b_out, out);
}

// Round 7
// 44.767 us; speedup vs baseline: 1.3910x; 1.0491x over previous
//
#include <hip/hip_runtime.h>

#define CS 384
#define CH 32
#define CZ 128
#define LL 512
#define C4 (CZ * CH)   // 4096 combined (z,a) columns
#define EPSV 1e-5f

typedef __attribute__((ext_vector_type(8))) short bf16x8;
typedef __attribute__((ext_vector_type(4))) float f32x4;

static __device__ __forceinline__ unsigned short f2bf(float x) {
  union { float f; unsigned int u; } c; c.f = x;
  unsigned int r = c.u + 0x7FFFu + ((c.u >> 16) & 1u);  // RNE
  return (unsigned short)(r >> 16);
}
static __device__ __forceinline__ unsigned int pk2(float lo, float hi) {
  return (unsigned int)f2bf(lo) | ((unsigned int)f2bf(hi) << 16);
}

// ---------------- Kernel 1: [blocks 0..511] LayerNorm+proj -> bf16 A,B --------
// ----------------           [blocks 512..543] W transpose -> bf16 Wt ----------
__global__ __launch_bounds__(256) void prep_kernel(
    const float* __restrict__ s, const float* __restrict__ gamma,
    const float* __restrict__ beta,
    const float* __restrict__ w1, const float* __restrict__ b1,
    const float* __restrict__ w2, const float* __restrict__ b2,
    const float* __restrict__ w_out,
    unsigned short* __restrict__ Abf, unsigned short* __restrict__ Bbf,
    unsigned short* __restrict__ Wt) {
  __shared__ union {
    struct { float sn[CS]; float red[256]; float wred[8]; } ln;
    float wl[CH * CZ];
  } sm;
  int tid = threadIdx.x;

  if (blockIdx.x < LL) {
    int l = blockIdx.x;
    const float* srow = s + l * CS;
    float lsum = 0.f, lsq = 0.f;
    for (int c = tid; c < CS; c += 256) {
      float x = srow[c]; sm.ln.sn[c] = x; lsum += x; lsq += x * x;
    }
    #pragma unroll
    for (int off = 32; off > 0; off >>= 1) {
      lsum += __shfl_down(lsum, off);
      lsq  += __shfl_down(lsq, off);
    }
    int wv = tid >> 6;
    if ((tid & 63) == 0) { sm.ln.wred[wv] = lsum; sm.ln.wred[4 + wv] = lsq; }
    __syncthreads();
    float s1 = sm.ln.wred[0] + sm.ln.wred[1] + sm.ln.wred[2] + sm.ln.wred[3];
    float s2 = sm.ln.wred[4] + sm.ln.wred[5] + sm.ln.wred[6] + sm.ln.wred[7];
    float mu = s1 * (1.0f / CS);
    float var = s2 * (1.0f / CS) - mu * mu;
    float rstd = rsqrtf(var + EPSV);

    for (int c = tid; c < CS; c += 256)
      sm.ln.sn[c] = (sm.ln.sn[c] - mu) * rstd * gamma[c] + beta[c];
    __syncthreads();

    int o = tid & 63, q = tid >> 6;
    int h = o & 31;
    const float* w = (o < CH) ? w1 : w2;
    float acc = 0.f;
    int c0 = q * 96;
    #pragma unroll 8
    for (int c = c0; c < c0 + 96; ++c) acc += sm.ln.sn[c] * w[c * CH + h];
    sm.ln.red[tid] = acc; __syncthreads();
    if (tid < 64) {
      float r = sm.ln.red[tid] + sm.ln.red[tid + 64] + sm.ln.red[tid + 128] +
                sm.ln.red[tid + 192];
      if (o < CH) Abf[l * CH + h] = f2bf(r + b1[h]);
      else        Bbf[l * CH + h] = f2bf(r + b2[h]);
    }
  } else {
    int a = blockIdx.x - LL;  // 0..31
    const float4* Wg = (const float4*)(w_out + (size_t)a * CH * CZ);
    float4* Wl4 = (float4*)sm.wl;
    #pragma unroll
    for (int v = 0; v < 4; ++v) Wl4[tid + v * 256] = Wg[tid + v * 256];
    __syncthreads();
    int z = tid >> 1, bh = tid & 1;  // z 0..127, b-half 0..1
    unsigned int dw[8];
    #pragma unroll
    for (int k = 0; k < 8; ++k) {
      unsigned short lo = f2bf(sm.wl[(bh * 16 + 2 * k) * CZ + z]);
      unsigned short hi = f2bf(sm.wl[(bh * 16 + 2 * k + 1) * CZ + z]);
      dw[k] = (unsigned int)lo | ((unsigned int)hi << 16);
    }
    unsigned int* dst =
        (unsigned int*)((char*)Wt + ((size_t)z * CH + a) * 64 + bh * 32);
    *(uint4*)dst = make_uint4(dw[0], dw[1], dw[2], dw[3]);
    *(uint4*)(dst + 4) = make_uint4(dw[4], dw[5], dw[6], dw[7]);
  }
}

// ---------------- Kernel 2: Tt[j][c] = sum_b Bbf[j,b] * Wt[c,b] (bf16 out) ----
__global__ __launch_bounds__(64) void tmat_kernel(
    const unsigned short* __restrict__ Bbf, const unsigned short* __restrict__ Wt,
    unsigned short* __restrict__ Tt) {
  int jt = blockIdx.x;   // 0..31 -> 16 j's
  int cq = blockIdx.y;   // 0..31 -> 8 c-tiles of 16
  int l = threadIdx.x;
  int q = l >> 4, r = l & 15;
  bf16x8 bfrag = *(const bf16x8*)(Bbf + (size_t)(jt * 16 + r) * CH + 8 * q);
  int j = jt * 16 + r;
  f32x4 zer = {0.f, 0.f, 0.f, 0.f};
  #pragma unroll
  for (int t = 0; t < 8; ++t) {
    int cbase = cq * 128 + t * 16;
    bf16x8 wfrag = *(const bf16x8*)(Wt + (size_t)(cbase + r) * CH + 8 * q);
    f32x4 acc = __builtin_amdgcn_mfma_f32_16x16x32_bf16(wfrag, bfrag, zer, 0, 0, 0);
    uint2 st;
    st.x = pk2(acc[0], acc[1]);
    st.y = pk2(acc[2], acc[3]);
    *(uint2*)(&Tt[(size_t)j * C4 + cbase + 4 * q]) = st;
  }
}

// ---------------- Kernel 3: out[i,j,:] = A[i,:] . T[j,:,:] + b_out ------------
// Linear grid 2048 with XCD-contiguous-j swizzle: each XCD gets a dense run of
// consecutive j for one it -> adjacent 512-B output chunks per i-row are
// written back-to-back in time (DRAM row-buffer hits). No LDS, no barriers.
__global__ __launch_bounds__(256) void outer_mfma(
    const unsigned short* __restrict__ Abf, const unsigned short* __restrict__ Tt,
    const float* __restrict__ b_out, float* __restrict__ out) {
  unsigned n = blockIdx.x;           // 0..2047
  unsigned xcd = n & 7, idx = n >> 3;
  unsigned wu = xcd * 256 + idx;     // bijective: 2048 = 8 * 256
  int it = wu >> 9;                  // 0..3
  int j  = wu & 511;                 // 0..511
  int tid = threadIdx.x;
  int w = tid >> 6, l = tid & 63, q = l >> 4, r = l & 15;
  int ib = it * 128 + w * 32;

  bf16x8 af0 = *(const bf16x8*)(Abf + (size_t)(ib + r) * CH + 8 * q);
  bf16x8 af1 = *(const bf16x8*)(Abf + (size_t)(ib + 16 + r) * CH + 8 * q);
  const unsigned short* Tj = Tt + (size_t)j * C4;

  #pragma unroll
  for (int zt = 0; zt < 8; ++zt) {
    f32x4 bo = *(const f32x4*)(b_out + zt * 16 + 4 * q);
    bf16x8 tf = *(const bf16x8*)(Tj + (size_t)(zt * 16 + r) * CH + 8 * q);
    f32x4 a0 = __builtin_amdgcn_mfma_f32_16x16x32_bf16(tf, af0, bo, 0, 0, 0);
    f32x4 a1 = __builtin_amdgcn_mfma_f32_16x16x32_bf16(tf, af1, bo, 0, 0, 0);
    // D: col = r -> i, rows = zt*16 + 4q + reg -> 4 consecutive z.
    float* o0 = out + ((size_t)(ib + r) * LL + j) * CZ + zt * 16 + 4 * q;
    float* o1 = out + ((size_t)(ib + 16 + r) * LL + j) * CZ + zt * 16 + 4 * q;
    *(f32x4*)o0 = a0;
    *(f32x4*)o1 = a1;
  }
}

extern "C" void kernel_launch(void* const* d_in, const int* in_sizes, int n_in,
                              void* d_out, int out_size, void* d_ws, size_t ws_size,
                              hipStream_t stream) {
  const float* s     = (const float*)d_in[0];
  const float* gam   = (const float*)d_in[1];
  const float* bet   = (const float*)d_in[2];
  const float* w1    = (const float*)d_in[3];
  const float* b1    = (const float*)d_in[4];
  const float* w2    = (const float*)d_in[5];
  const float* b2    = (const float*)d_in[6];
  const float* w_out = (const float*)d_in[7];
  const float* b_out = (const float*)d_in[8];
  float* out = (float*)d_out;

  char* ws = (char*)d_ws;
  unsigned short* Abf = (unsigned short*)(ws);            // 32 KB
  unsigned short* Bbf = (unsigned short*)(ws + 32768);    // 32 KB
  unsigned short* Wt  = (unsigned short*)(ws + 65536);    // 256 KB
  unsigned short* Tt  = (unsigned short*)(ws + 327680);   // 4 MB

  prep_kernel<<<LL + CH, 256, 0, stream>>>(s, gam, bet, w1, b1, w2, b2, w_out,
                                           Abf, Bbf, Wt);
  tmat_kernel<<<dim3(32, 32), 64, 0, stream>>>(Bbf, Wt, Tt);
  outer_mfma<<<2048, 256, 0, stream>>>(Abf, Tt, b_out, out);
}

// Round 8
// 42.311 us; speedup vs baseline: 1.4717x; 1.0580x over previous
//
#include <hip/hip_runtime.h>

#define CS 384
#define CH 32
#define CZ 128
#define LL 512
#define C4 (CZ * CH)   // 4096 combined (z,a) columns
#define EPSV 1e-5f

typedef __attribute__((ext_vector_type(8))) short bf16x8;
typedef __attribute__((ext_vector_type(4))) float f32x4;

static __device__ __forceinline__ unsigned short f2bf(float x) {
  union { float f; unsigned int u; } c; c.f = x;
  unsigned int r = c.u + 0x7FFFu + ((c.u >> 16) & 1u);  // RNE
  return (unsigned short)(r >> 16);
}
static __device__ __forceinline__ unsigned int pk2(float lo, float hi) {
  return (unsigned int)f2bf(lo) | ((unsigned int)f2bf(hi) << 16);
}

// ---------------- Kernel 1: [blocks 0..511] LayerNorm+proj -> bf16 A,B --------
// ----------------           [blocks 512..543] W transpose -> bf16 Wt ----------
__global__ __launch_bounds__(256) void prep_kernel(
    const float* __restrict__ s, const float* __restrict__ gamma,
    const float* __restrict__ beta,
    const float* __restrict__ w1, const float* __restrict__ b1,
    const float* __restrict__ w2, const float* __restrict__ b2,
    const float* __restrict__ w_out,
    unsigned short* __restrict__ Abf, unsigned short* __restrict__ Bbf,
    unsigned short* __restrict__ Wt) {
  __shared__ union {
    struct { float sn[CS]; float red[256]; float wred[8]; } ln;
    float wl[CH * CZ];
  } sm;
  int tid = threadIdx.x;

  if (blockIdx.x < LL) {
    int l = blockIdx.x;
    const float* srow = s + l * CS;
    float lsum = 0.f, lsq = 0.f;
    for (int c = tid; c < CS; c += 256) {
      float x = srow[c]; sm.ln.sn[c] = x; lsum += x; lsq += x * x;
    }
    #pragma unroll
    for (int off = 32; off > 0; off >>= 1) {
      lsum += __shfl_down(lsum, off);
      lsq  += __shfl_down(lsq, off);
    }
    int wv = tid >> 6;
    if ((tid & 63) == 0) { sm.ln.wred[wv] = lsum; sm.ln.wred[4 + wv] = lsq; }
    __syncthreads();
    float s1 = sm.ln.wred[0] + sm.ln.wred[1] + sm.ln.wred[2] + sm.ln.wred[3];
    float s2 = sm.ln.wred[4] + sm.ln.wred[5] + sm.ln.wred[6] + sm.ln.wred[7];
    float mu = s1 * (1.0f / CS);
    float var = s2 * (1.0f / CS) - mu * mu;
    float rstd = rsqrtf(var + EPSV);

    for (int c = tid; c < CS; c += 256)
      sm.ln.sn[c] = (sm.ln.sn[c] - mu) * rstd * gamma[c] + beta[c];
    __syncthreads();

    int o = tid & 63, q = tid >> 6;
    int h = o & 31;
    const float* w = (o < CH) ? w1 : w2;
    float acc = 0.f;
    int c0 = q * 96;
    #pragma unroll 8
    for (int c = c0; c < c0 + 96; ++c) acc += sm.ln.sn[c] * w[c * CH + h];
    sm.ln.red[tid] = acc; __syncthreads();
    if (tid < 64) {
      float r = sm.ln.red[tid] + sm.ln.red[tid + 64] + sm.ln.red[tid + 128] +
                sm.ln.red[tid + 192];
      if (o < CH) Abf[l * CH + h] = f2bf(r + b1[h]);
      else        Bbf[l * CH + h] = f2bf(r + b2[h]);
    }
  } else {
    int a = blockIdx.x - LL;  // 0..31
    const float4* Wg = (const float4*)(w_out + (size_t)a * CH * CZ);
    float4* Wl4 = (float4*)sm.wl;
    #pragma unroll
    for (int v = 0; v < 4; ++v) Wl4[tid + v * 256] = Wg[tid + v * 256];
    __syncthreads();
    int z = tid >> 1, bh = tid & 1;  // z 0..127, b-half 0..1
    unsigned int dw[8];
    #pragma unroll
    for (int k = 0; k < 8; ++k) {
      unsigned short lo = f2bf(sm.wl[(bh * 16 + 2 * k) * CZ + z]);
      unsigned short hi = f2bf(sm.wl[(bh * 16 + 2 * k + 1) * CZ + z]);
      dw[k] = (unsigned int)lo | ((unsigned int)hi << 16);
    }
    unsigned int* dst =
        (unsigned int*)((char*)Wt + ((size_t)z * CH + a) * 64 + bh * 32);
    *(uint4*)dst = make_uint4(dw[0], dw[1], dw[2], dw[3]);
    *(uint4*)(dst + 4) = make_uint4(dw[4], dw[5], dw[6], dw[7]);
  }
}

// ---------------- Kernel 2: Tt[j][c] = sum_b Bbf[j,b] * Wt[c,b] (bf16 out) ----
__global__ __launch_bounds__(64) void tmat_kernel(
    const unsigned short* __restrict__ Bbf, const unsigned short* __restrict__ Wt,
    unsigned short* __restrict__ Tt) {
  int jt = blockIdx.x;   // 0..31 -> 16 j's
  int cq = blockIdx.y;   // 0..31 -> 8 c-tiles of 16
  int l = threadIdx.x;
  int q = l >> 4, r = l & 15;
  bf16x8 bfrag = *(const bf16x8*)(Bbf + (size_t)(jt * 16 + r) * CH + 8 * q);
  int j = jt * 16 + r;
  f32x4 zer = {0.f, 0.f, 0.f, 0.f};
  #pragma unroll
  for (int t = 0; t < 8; ++t) {
    int cbase = cq * 128 + t * 16;
    bf16x8 wfrag = *(const bf16x8*)(Wt + (size_t)(cbase + r) * CH + 8 * q);
    f32x4 acc = __builtin_amdgcn_mfma_f32_16x16x32_bf16(wfrag, bfrag, zer, 0, 0, 0);
    uint2 st;
    st.x = pk2(acc[0], acc[1]);
    st.y = pk2(acc[2], acc[3]);
    *(uint2*)(&Tt[(size_t)j * C4 + cbase + 4 * q]) = st;
  }
}

// ---------------- Kernel 3: out[i,j,:] = A[i,:] . T[j,:,:] + b_out ------------
// Write-locality restructure: grid 256 (1 block/CU), block = 512 thr = 8 waves.
// Block owns (i-tile of 16) x (j-tile of 64); wave w owns 8 CONSECUTIVE j and
// loops them serially -> each of its 16 i-row streams advances sequentially in
// 512-B steps (4-KB contiguous runs, DRAM row-buffer hits). j-tile = XCD id so
// the 512-KB Tt slice is L2-hot per XCD.
__global__ __launch_bounds__(512) void outer_mfma(
    const unsigned short* __restrict__ Abf, const unsigned short* __restrict__ Tt,
    const float* __restrict__ b_out, float* __restrict__ out) {
  unsigned n = blockIdx.x;      // 0..255
  int jt = n & 7;               // XCD-affine j-tile (64 j each)
  int it = n >> 3;              // 0..31 -> 16 i each
  int tid = threadIdx.x;
  int w = tid >> 6, l = tid & 63, q = l >> 4, r = l & 15;
  int ib = it * 16;

  // A-frag: lane holds A[ib + r][a = 8q..8q+7].
  bf16x8 af = *(const bf16x8*)(Abf + (size_t)(ib + r) * CH + 8 * q);

  // Bias (C operand) per z-tile: 4 consecutive z for this lane.
  f32x4 bo[8];
  #pragma unroll
  for (int zt = 0; zt < 8; ++zt) bo[zt] = *(const f32x4*)(b_out + zt * 16 + 4 * q);

  int j0 = jt * 64 + w * 8;
  float* orow = out + ((size_t)(ib + r) * LL) * CZ;

  #pragma unroll 2
  for (int jj = 0; jj < 8; ++jj) {
    int j = j0 + jj;
    const unsigned short* Tj = Tt + (size_t)j * C4;
    float* oj = orow + (size_t)j * CZ;
    #pragma unroll
    for (int zt = 0; zt < 8; ++zt) {
      bf16x8 tf = *(const bf16x8*)(Tj + (size_t)(zt * 16 + r) * CH + 8 * q);
      // D = Tt^T(z x a) . A(a x i) + bias: col=r -> i, rows 4q+reg -> 4 consecutive z.
      f32x4 d = __builtin_amdgcn_mfma_f32_16x16x32_bf16(tf, af, bo[zt], 0, 0, 0);
      *(f32x4*)(oj + zt * 16 + 4 * q) = d;
    }
  }
}

extern "C" void kernel_launch(void* const* d_in, const int* in_sizes, int n_in,
                              void* d_out, int out_size, void* d_ws, size_t ws_size,
                              hipStream_t stream) {
  const float* s     = (const float*)d_in[0];
  const float* gam   = (const float*)d_in[1];
  const float* bet   = (const float*)d_in[2];
  const float* w1    = (const float*)d_in[3];
  const float* b1    = (const float*)d_in[4];
  const float* w2    = (const float*)d_in[5];
  const float* b2    = (const float*)d_in[6];
  const float* w_out = (const float*)d_in[7];
  const float* b_out = (const float*)d_in[8];
  float* out = (float*)d_out;

  char* ws = (char*)d_ws;
  unsigned short* Abf = (unsigned short*)(ws);            // 32 KB
  unsigned short* Bbf = (unsigned short*)(ws + 32768);    // 32 KB
  unsigned short* Wt  = (unsigned short*)(ws + 65536);    // 256 KB
  unsigned short* Tt  = (unsigned short*)(ws + 327680);   // 4 MB

  prep_kernel<<<LL + CH, 256, 0, stream>>>(s, gam, bet, w1, b1, w2, b2, w_out,
                                           Abf, Bbf, Wt);
  tmat_kernel<<<dim3(32, 32), 64, 0, stream>>>(Bbf, Wt, Tt);
  outer_mfma<<<256, 512, 0, stream>>>(Abf, Tt, b_out, out);
}